// Round 12
// baseline (750.910 us; speedup 1.0000x reference)
//
#include <hip/hip_runtime.h>
#include <cstdint>

typedef unsigned short u16;
typedef __bf16 bf16x8 __attribute__((ext_vector_type(8)));
typedef float f32x4 __attribute__((ext_vector_type(4)));

__device__ __forceinline__ u16 f2bf(float f) {
    uint32_t u = __float_as_uint(f);
    u += 0x7FFFu + ((u >> 16) & 1u);
    return (u16)(u >> 16);
}
__device__ __forceinline__ float bf2f(u16 v) {
    return __uint_as_float((uint32_t)v << 16);
}

// async global->LDS, 16B per lane (m97: emits global_load_lds_dwordx4)
__device__ __forceinline__ void gload16(const u16* g, u16* l) {
    __builtin_amdgcn_global_load_lds(
        (const __attribute__((address_space(1))) uint32_t*)g,
        (__attribute__((address_space(3))) uint32_t*)l, 16, 0, 0);
}

// XCD-aware work swizzle (bijective for these grids).
__device__ __forceinline__ void swz(int& n_idx, int& m_idx, int& z_idx) {
    const int nx = gridDim.x, ny = gridDim.y;
    int lid = blockIdx.x + nx * (blockIdx.y + ny * blockIdx.z);
    int g = lid & 7, h = lid >> 3;
    n_idx = h % nx;
    int pair = (h / nx) * 8 + g;
    m_idx = pair % ny;
    z_idx = pair / ny;
}

// ---------------------------------------------------------------------------
// Dtype detect (1=fp32 storage, 0=bf16).
// ---------------------------------------------------------------------------
__global__ __launch_bounds__(256) void k_detect(const u16* __restrict__ x,
                                                int* __restrict__ flag) {
    const int t = threadIdx.x;
    uint32_t mx = 0;
    for (int i = 0; i < 256; i++) {
        uint32_t v = (uint32_t)x[i * 256 + t] & 0x7FFFu;
        mx = mx > v ? mx : v;
    }
    for (int off = 32; off > 0; off >>= 1) {
        uint32_t o = (uint32_t)__shfl_xor((int)mx, off);
        mx = mx > o ? mx : o;
    }
    __shared__ uint32_t r[4];
    if ((t & 63) == 0) r[t >> 6] = mx;
    __syncthreads();
    if (t == 0) {
        uint32_t a = r[0] > r[1] ? r[0] : r[1];
        uint32_t b = r[2] > r[3] ? r[2] : r[3];
        mx = a > b ? a : b;
        *flag = (mx > 0x5000u) ? 1 : 0;
    }
}

// ---------------------------------------------------------------------------
// Canonicalize weights/vectors into bf16 (Wc: wq|wk|wv|wp, Bc: gw|gb|bq|bk|bv|bp)
// ---------------------------------------------------------------------------
__global__ __launch_bounds__(256) void k_cvt_wb(const void* wq, const void* wk,
                                                const void* wv, const void* wp,
                                                const void* gw, const void* gb,
                                                const void* bq, const void* bk,
                                                const void* bv, const void* bp,
                                                const int* __restrict__ flag,
                                                u16* __restrict__ Wc,
                                                u16* __restrict__ Bc) {
    const int mode = *flag;
    int i = blockIdx.x * 256 + threadIdx.x;
    if (i >= 1048576 + 3072) return;
    const void* src;
    u16* dst;
    int off;
    if (i < 1048576) {
        int which = i >> 18;
        off = i & 262143;
        src = which == 0 ? wq : which == 1 ? wk : which == 2 ? wv : wp;
        dst = Wc + i;
    } else {
        int j = i - 1048576;
        int which = j >> 9;
        off = j & 511;
        src = which == 0 ? gw : which == 1 ? gb : which == 2 ? bq
            : which == 3 ? bk : which == 4 ? bv : bp;
        dst = Bc + j;
    }
    *dst = mode ? f2bf(((const float*)src)[off]) : ((const u16*)src)[off];
}

// ---------------------------------------------------------------------------
// GN stats: one block per (b,g); writes per-channel scale/shift (fp32).
// ---------------------------------------------------------------------------
__global__ __launch_bounds__(256) void k_gn_stats(const void* __restrict__ x_raw,
                                                  const u16* __restrict__ Bc,
                                                  const int* __restrict__ flag,
                                                  float* __restrict__ Sc,
                                                  float* __restrict__ Sh) {
    const int b = blockIdx.x >> 5, g = blockIdx.x & 31;
    const int mode = *flag;
    const int t = threadIdx.x;
    const int wave = t >> 6, lane = t & 63;
    float s = 0.f, ss = 0.f;
    if (mode) {
        const float4* xb = (const float4*)((const float*)x_raw +
                                           ((size_t)b * 512 + g * 16) * 4096);
        for (int it = 0; it < 64; it++) {
            float4 v = xb[it * 256 + t];
            s += v.x + v.y + v.z + v.w;
            ss += v.x * v.x + v.y * v.y + v.z * v.z + v.w * v.w;
        }
    } else {
        const uint4* xb = (const uint4*)((const u16*)x_raw +
                                         ((size_t)b * 512 + g * 16) * 4096);
        for (int it = 0; it < 32; it++) {
            uint4 v = xb[it * 256 + t];
            uint32_t w[4] = {v.x, v.y, v.z, v.w};
            for (int j = 0; j < 4; j++) {
                float a = __uint_as_float(w[j] << 16);
                float c = __uint_as_float(w[j] & 0xFFFF0000u);
                s += a + c;
                ss += a * a + c * c;
            }
        }
    }
    for (int off = 32; off > 0; off >>= 1) {
        s += __shfl_xor(s, off);
        ss += __shfl_xor(ss, off);
    }
    __shared__ float rs[4], rss[4];
    if (lane == 0) { rs[wave] = s; rss[wave] = ss; }
    __syncthreads();
    s = rs[0] + rs[1] + rs[2] + rs[3];
    ss = rss[0] + rss[1] + rss[2] + rss[3];
    const float mean = s * (1.f / 65536.f);
    const float var = ss * (1.f / 65536.f) - mean * mean;
    const float rstd = rsqrtf(var + 1e-6f);
    if (t < 16) {
        int c = g * 16 + t;
        float w = bf2f(Bc[c]);
        Sc[b * 512 + c] = rstd * w;
        Sh[b * 512 + c] = bf2f(Bc[512 + c]) - mean * rstd * w;
    }
}

// ---------------------------------------------------------------------------
// GN apply + transpose -> HT[b][p][c] (contiguous 1KB rows). grid (64, 8).
// ---------------------------------------------------------------------------
#define TPAD 520
__global__ __launch_bounds__(256) void k_gn_apply(const void* __restrict__ x_raw,
                                                  const int* __restrict__ flag,
                                                  const float* __restrict__ Sc,
                                                  const float* __restrict__ Sh,
                                                  u16* __restrict__ HT) {
    __shared__ u16 tile[64 * TPAD];
    __shared__ float sSc[512], sSh[512];
    const int b = blockIdx.y;
    const int p0 = blockIdx.x * 64;
    const int mode = *flag;
    const int t = threadIdx.x;
    sSc[t] = Sc[b * 512 + t]; sSc[t + 256] = Sc[b * 512 + t + 256];
    sSh[t] = Sh[b * 512 + t]; sSh[t + 256] = Sh[b * 512 + t + 256];
    __syncthreads();
    for (int it = 0; it < 16; it++) {
        int li = it * 256 + t;
        int c = li >> 3;
        int pj = (li & 7) * 8;
        float v[8];
        if (mode) {
            const float* xr = (const float*)x_raw + ((size_t)b * 512 + c) * 4096 + p0 + pj;
            float4 a = *(const float4*)xr;
            float4 d = *(const float4*)(xr + 4);
            v[0] = a.x; v[1] = a.y; v[2] = a.z; v[3] = a.w;
            v[4] = d.x; v[5] = d.y; v[6] = d.z; v[7] = d.w;
        } else {
            const u16* xr = (const u16*)x_raw + ((size_t)b * 512 + c) * 4096 + p0 + pj;
            uint4 a = *(const uint4*)xr;
            uint32_t w[4] = {a.x, a.y, a.z, a.w};
            for (int j = 0; j < 4; j++) {
                v[2 * j] = __uint_as_float(w[j] << 16);
                v[2 * j + 1] = __uint_as_float(w[j] & 0xFFFF0000u);
            }
        }
        float sc = sSc[c], sh = sSh[c];
        for (int k = 0; k < 8; k++)
            tile[(pj + k) * TPAD + c] = f2bf(v[k] * sc + sh);
    }
    __syncthreads();
    u16* H = HT + (size_t)b * 2097152 + (size_t)p0 * 512;
    for (int it = 0; it < 16; it++) {
        int ch = it * 256 + t;
        int pp = ch >> 6;
        int cc = (ch & 63) * 8;
        *(uint4*)&H[(size_t)pp * 512 + cc] = *(const uint4*)&tile[pp * TPAD + cc];
    }
}

// ---------------------------------------------------------------------------
// QKV, 256x256 tile, counted-vmcnt fine-interleaved schedule (R11-verified).
// grid (32, 24). 768 blocks = 3 full CU rounds.
// ---------------------------------------------------------------------------
__global__ __launch_bounds__(512, 2) void k_qkv(const u16* __restrict__ HT,
                                                const u16* __restrict__ Wc,
                                                const u16* __restrict__ Bc,
                                                u16* __restrict__ QT,
                                                u16* __restrict__ KT,
                                                u16* __restrict__ V) {
    __shared__ __align__(16) u16 lds[65536];   // 128 KiB: A0|B0|A1|B1 @16384
    int xI, bs, dz;
    swz(xI, bs, dz);
    const int b = bs / 3, s = bs % 3;
    const u16* Bb = Bc + 1024 + s * 512;
    int m0, n0, ldo, bias_by_row;
    const u16 *A, *B;
    u16* O;
    if (s < 2) {
        m0 = (xI >> 1) * 256; n0 = (xI & 1) * 256;
        A = HT + (size_t)b * 2097152; B = Wc + (size_t)s * 262144;
        O = (s == 0 ? QT : KT) + (size_t)b * 2097152; ldo = 512; bias_by_row = 0;
    } else {
        m0 = (xI & 1) * 256; n0 = (xI >> 1) * 256;
        A = Wc + (size_t)2 * 262144; B = HT + (size_t)b * 2097152;
        O = V + (size_t)b * 2097152; ldo = 4096; bias_by_row = 1;
    }

    const int t = threadIdx.x;
    const int wave = t >> 6, lane = t & 63;
    const int wm = (wave >> 2) * 128, wn = (wave & 3) * 64;   // 2m x 4n
    const int mf = lane & 15, quad = lane >> 4;
    const int fx = mf & 7;
    const int srow = t >> 3;      // 0..63 per sweep
    const int scol8 = t & 7;

    f32x4 acc[8][4];
#pragma unroll
    for (int i = 0; i < 8; i++)
#pragma unroll
        for (int j = 0; j < 4; j++)
            acc[i][j] = (f32x4){0.f, 0.f, 0.f, 0.f};

    auto issueA = [&](u16* dst, int h, int k0) {
#pragma unroll
        for (int ss = 0; ss < 2; ss++) {
            int row = h * 128 + ss * 64 + srow;
            gload16(A + (size_t)(m0 + row) * 512 + k0 + ((scol8 ^ (row & 7)) << 3),
                    dst + h * 8192 + ss * 4096 + t * 8);
        }
    };
    auto issueB = [&](u16* dst, int h, int k0) {
#pragma unroll
        for (int ss = 0; ss < 2; ss++) {
            int row = h * 128 + ss * 64 + srow;
            gload16(B + (size_t)(n0 + row) * 512 + k0 + ((scol8 ^ (row & 7)) << 3),
                    dst + h * 8192 + ss * 4096 + t * 8);
        }
    };

    issueA(lds, 0, 0); issueA(lds, 1, 0);
    issueB(lds + 16384, 0, 0); issueB(lds + 16384, 1, 0);

    for (int kt = 0; kt < 8; kt++) {
        u16* lA = (kt & 1) ? lds + 32768 : lds;
        u16* lB = lA + 16384;
        u16* pA = (kt & 1) ? lds : lds + 32768;
        u16* pB = pA + 16384;
        const int k0n = (kt + 1) << 6;
        const bool pf = kt < 7;
        asm volatile("" ::: "memory");
        __builtin_amdgcn_s_barrier();
        asm volatile("" ::: "memory");
        if (pf) {
            issueA(pA, 0, k0n);
            asm volatile("s_waitcnt vmcnt(2)" ::: "memory");
        } else {
            asm volatile("s_waitcnt vmcnt(0)" ::: "memory");
        }
        __builtin_amdgcn_s_barrier();
        asm volatile("" ::: "memory");

        bf16x8 af[8], bfr[2];
        int sl = (quad ^ fx) * 8;
#pragma unroll
        for (int i = 0; i < 8; i++)
            af[i] = *(const bf16x8*)&lA[(wm + i * 16 + mf) * 64 + sl];
#pragma unroll
        for (int j = 0; j < 2; j++)
            bfr[j] = *(const bf16x8*)&lB[(wn + j * 16 + mf) * 64 + sl];
        __builtin_amdgcn_s_setprio(1);
#pragma unroll
        for (int i = 0; i < 8; i++)
#pragma unroll
            for (int j = 0; j < 2; j++)
                acc[i][j] = __builtin_amdgcn_mfma_f32_16x16x32_bf16(af[i], bfr[j], acc[i][j], 0, 0, 0);
        __builtin_amdgcn_s_setprio(0);
        if (pf) issueA(pA, 1, k0n);
#pragma unroll
        for (int j = 0; j < 2; j++)
            bfr[j] = *(const bf16x8*)&lB[(wn + (2 + j) * 16 + mf) * 64 + sl];
        __builtin_amdgcn_s_setprio(1);
#pragma unroll
        for (int i = 0; i < 8; i++)
#pragma unroll
            for (int j = 0; j < 2; j++)
                acc[i][2 + j] = __builtin_amdgcn_mfma_f32_16x16x32_bf16(af[i], bfr[j], acc[i][2 + j], 0, 0, 0);
        __builtin_amdgcn_s_setprio(0);
        sl = ((4 + quad) ^ fx) * 8;
        if (pf) issueB(pB, 0, k0n);
#pragma unroll
        for (int i = 0; i < 8; i++)
            af[i] = *(const bf16x8*)&lA[(wm + i * 16 + mf) * 64 + sl];
#pragma unroll
        for (int j = 0; j < 2; j++)
            bfr[j] = *(const bf16x8*)&lB[(wn + j * 16 + mf) * 64 + sl];
        __builtin_amdgcn_s_setprio(1);
#pragma unroll
        for (int i = 0; i < 8; i++)
#pragma unroll
            for (int j = 0; j < 2; j++)
                acc[i][j] = __builtin_amdgcn_mfma_f32_16x16x32_bf16(af[i], bfr[j], acc[i][j], 0, 0, 0);
        __builtin_amdgcn_s_setprio(0);
        if (pf) issueB(pB, 1, k0n);
#pragma unroll
        for (int j = 0; j < 2; j++)
            bfr[j] = *(const bf16x8*)&lB[(wn + (2 + j) * 16 + mf) * 64 + sl];
        __builtin_amdgcn_s_setprio(1);
#pragma unroll
        for (int i = 0; i < 8; i++)
#pragma unroll
            for (int j = 0; j < 2; j++)
                acc[i][2 + j] = __builtin_amdgcn_mfma_f32_16x16x32_bf16(af[i], bfr[j], acc[i][2 + j], 0, 0, 0);
        __builtin_amdgcn_s_setprio(0);
    }

    // ---- epilogue: bias + full-tile bounce + coalesced store ----
    __syncthreads();
#pragma unroll
    for (int i = 0; i < 8; i++)
#pragma unroll
        for (int r = 0; r < 4; r++) {
            int row = wm + i * 16 + quad * 4 + r;
            int key = row & 7;
            float brow = bias_by_row ? bf2f(Bb[m0 + row]) : 0.f;
#pragma unroll
            for (int j = 0; j < 4; j++) {
                int col = wn + j * 16 + mf;
                float bias = bias_by_row ? brow : bf2f(Bb[n0 + col]);
                lds[row * 256 + (((col >> 3) ^ key) << 3) + (col & 7)] =
                    f2bf(acc[i][j][r] + bias);
            }
        }
    __syncthreads();
    for (int p = 0; p < 16; p++) {
        int idx = p * 512 + t;
        int row = idx >> 5, chunk = idx & 31;
        uint4 v = *(const uint4*)&lds[row * 256 + ((chunk ^ (row & 7)) << 3)];
        *(uint4*)&O[(size_t)(m0 + row) * ldo + n0 + chunk * 8] = v;
    }
}

// ---------------------------------------------------------------------------
// Local-batch S pointer: l==0 -> HT region, else tail + (l-1)*16M.
// ---------------------------------------------------------------------------
__device__ __forceinline__ u16* s_ptr(u16* S_ht, u16* S_tail, int l) {
    return l == 0 ? S_ht : S_tail + (size_t)(l - 1) * 16777216;
}

// ---------------------------------------------------------------------------
// Scores, 256x256 tile, 8-wave counted-vmcnt fine-interleaved schedule
// (R9-verified). grid (16,16,nb), 512 thr.
// ---------------------------------------------------------------------------
__global__ __launch_bounds__(512, 2) void k_scores(const u16* __restrict__ QT,
                                                   const u16* __restrict__ KT,
                                                   u16* __restrict__ S_ht,
                                                   u16* __restrict__ S_tail,
                                                   float* __restrict__ Part,
                                                   int b0) {
    __shared__ __align__(16) u16 lds[65536];   // 128 KiB: A0|B0|A1|B1 @16384
    int nI, mI, l;
    swz(nI, mI, l);
    const int n0 = nI * 256;
    const int m0 = mI * 256;
    const int b = b0 + l;
    const u16* Aq = QT + (size_t)b * 2097152;
    const u16* Bk = KT + (size_t)b * 2097152;

    const int t = threadIdx.x;
    const int wave = t >> 6, lane = t & 63;
    const int wm = (wave >> 2) * 128, wn = (wave & 3) * 64;   // 2m x 4n
    const int mf = lane & 15, quad = lane >> 4;
    const int fx = mf & 7;
    const int srow = t >> 3;      // 0..63 per sweep
    const int scol8 = t & 7;

    f32x4 acc[8][4];
#pragma unroll
    for (int i = 0; i < 8; i++)
#pragma unroll
        for (int j = 0; j < 4; j++)
            acc[i][j] = (f32x4){0.f, 0.f, 0.f, 0.f};

    auto issueA = [&](u16* dst, int h, int k0) {
#pragma unroll
        for (int s = 0; s < 2; s++) {
            int row = h * 128 + s * 64 + srow;
            gload16(Aq + (size_t)(m0 + row) * 512 + k0 + ((scol8 ^ (row & 7)) << 3),
                    dst + h * 8192 + s * 4096 + t * 8);
        }
    };
    auto issueB = [&](u16* dst, int h, int k0) {
#pragma unroll
        for (int s = 0; s < 2; s++) {
            int row = h * 128 + s * 64 + srow;
            gload16(Bk + (size_t)(n0 + row) * 512 + k0 + ((scol8 ^ (row & 7)) << 3),
                    dst + h * 8192 + s * 4096 + t * 8);
        }
    };

    issueA(lds, 0, 0); issueA(lds, 1, 0);
    issueB(lds + 16384, 0, 0); issueB(lds + 16384, 1, 0);

    for (int kt = 0; kt < 8; kt++) {
        u16* lA = (kt & 1) ? lds + 32768 : lds;
        u16* lB = lA + 16384;
        u16* pA = (kt & 1) ? lds : lds + 32768;
        u16* pB = pA + 16384;
        const int k0n = (kt + 1) << 6;
        const bool pf = kt < 7;
        asm volatile("" ::: "memory");
        __builtin_amdgcn_s_barrier();
        asm volatile("" ::: "memory");
        if (pf) {
            issueA(pA, 0, k0n);
            asm volatile("s_waitcnt vmcnt(2)" ::: "memory");
        } else {
            asm volatile("s_waitcnt vmcnt(0)" ::: "memory");
        }
        __builtin_amdgcn_s_barrier();
        asm volatile("" ::: "memory");

        bf16x8 af[8], bfr[2];
        int sl = (quad ^ fx) * 8;
#pragma unroll
        for (int i = 0; i < 8; i++)
            af[i] = *(const bf16x8*)&lA[(wm + i * 16 + mf) * 64 + sl];
#pragma unroll
        for (int j = 0; j < 2; j++)
            bfr[j] = *(const bf16x8*)&lB[(wn + j * 16 + mf) * 64 + sl];
        __builtin_amdgcn_s_setprio(1);
#pragma unroll
        for (int i = 0; i < 8; i++)
#pragma unroll
            for (int j = 0; j < 2; j++)
                acc[i][j] = __builtin_amdgcn_mfma_f32_16x16x32_bf16(af[i], bfr[j], acc[i][j], 0, 0, 0);
        __builtin_amdgcn_s_setprio(0);
        if (pf) issueA(pA, 1, k0n);
#pragma unroll
        for (int j = 0; j < 2; j++)
            bfr[j] = *(const bf16x8*)&lB[(wn + (2 + j) * 16 + mf) * 64 + sl];
        __builtin_amdgcn_s_setprio(1);
#pragma unroll
        for (int i = 0; i < 8; i++)
#pragma unroll
            for (int j = 0; j < 2; j++)
                acc[i][2 + j] = __builtin_amdgcn_mfma_f32_16x16x32_bf16(af[i], bfr[j], acc[i][2 + j], 0, 0, 0);
        __builtin_amdgcn_s_setprio(0);
        sl = ((4 + quad) ^ fx) * 8;
        if (pf) issueB(pB, 0, k0n);
#pragma unroll
        for (int i = 0; i < 8; i++)
            af[i] = *(const bf16x8*)&lA[(wm + i * 16 + mf) * 64 + sl];
#pragma unroll
        for (int j = 0; j < 2; j++)
            bfr[j] = *(const bf16x8*)&lB[(wn + j * 16 + mf) * 64 + sl];
        __builtin_amdgcn_s_setprio(1);
#pragma unroll
        for (int i = 0; i < 8; i++)
#pragma unroll
            for (int j = 0; j < 2; j++)
                acc[i][j] = __builtin_amdgcn_mfma_f32_16x16x32_bf16(af[i], bfr[j], acc[i][j], 0, 0, 0);
        __builtin_amdgcn_s_setprio(0);
        if (pf) issueB(pB, 1, k0n);
#pragma unroll
        for (int j = 0; j < 2; j++)
            bfr[j] = *(const bf16x8*)&lB[(wn + (2 + j) * 16 + mf) * 64 + sl];
        __builtin_amdgcn_s_setprio(1);
#pragma unroll
        for (int i = 0; i < 8; i++)
#pragma unroll
            for (int j = 0; j < 2; j++)
                acc[i][2 + j] = __builtin_amdgcn_mfma_f32_16x16x32_bf16(af[i], bfr[j], acc[i][2 + j], 0, 0, 0);
        __builtin_amdgcn_s_setprio(0);
    }

    const float scale = 0.04419417382415922f;
    __syncthreads();
#pragma unroll
    for (int i = 0; i < 8; i++)
#pragma unroll
        for (int r = 0; r < 4; r++) {
            int row = wm + i * 16 + quad * 4 + r;
            int key = row & 7;
#pragma unroll
            for (int j = 0; j < 4; j++) {
                int col = wn + j * 16 + mf;
                lds[row * 256 + (((col >> 3) ^ key) << 3) + (col & 7)] =
                    f2bf(__expf(acc[i][j][r] * scale));
            }
        }
    __syncthreads();
    u16* Sb = s_ptr(S_ht, S_tail, l);
    float* pr = Part + ((size_t)b * 16 + nI) * 4096 + m0;
    for (int p = 0; p < 16; p++) {
        int idx = p * 512 + t;
        int row = idx >> 5, chunk = idx & 31;
        uint4 v = *(const uint4*)&lds[row * 256 + ((chunk ^ (row & 7)) << 3)];
        uint32_t w[4] = {v.x, v.y, v.z, v.w};
        float s = 0.f;
        for (int q2 = 0; q2 < 4; q2++)
            s += __uint_as_float(w[q2] << 16) + __uint_as_float(w[q2] & 0xFFFF0000u);
        for (int off = 16; off > 0; off >>= 1) s += __shfl_xor(s, off);
        if ((lane & 31) == 0) pr[row] = s;
        *(uint4*)&Sb[(size_t)(m0 + row) * 4096 + n0 + chunk * 8] = v;
    }
}

// ---------------------------------------------------------------------------
// PV split-K=2, 128x256 tile, 8-wave counted-vmcnt fine-interleaved schedule
// (R10-verified). grid (2, 32, 2*nb) = 256 blocks/launch.
// ---------------------------------------------------------------------------
__global__ __launch_bounds__(512, 2) void k_pv_split(u16* __restrict__ S_ht,
                                                     u16* __restrict__ S_tail,
                                                     const u16* __restrict__ V,
                                                     u16* __restrict__ QT,
                                                     u16* __restrict__ KT,
                                                     int b0) {
    __shared__ __align__(16) u16 lds[49152];
    int nI, mI, zI;
    swz(nI, mI, zI);
    const int n0 = nI * 256;
    const int m0 = mI * 128;
    const int l = zI >> 1, split = zI & 1, b = b0 + l;
    const u16* A = s_ptr(S_ht, S_tail, l) + split * 2048;
    const u16* B = V + (size_t)b * 2097152 + split * 2048;

    const int t = threadIdx.x;
    const int wave = t >> 6, lane = t & 63;
    const int wm = (wave >> 2) * 64, wn = (wave & 3) * 64;   // 2m x 4n
    const int mf = lane & 15, quad = lane >> 4;
    const int fx = mf & 7;
    const int srow = t >> 3;      // 0..63
    const int scol8 = t & 7;

    f32x4 acc[4][4];
#pragma unroll
    for (int i = 0; i < 4; i++)
#pragma unroll
        for (int j = 0; j < 4; j++)
            acc[i][j] = (f32x4){0.f, 0.f, 0.f, 0.f};

    auto issueA = [&](u16* dst, int k0) {
#pragma unroll
        for (int s = 0; s < 2; s++) {
            int row = s * 64 + srow;
            gload16(A + (size_t)(m0 + row) * 4096 + k0 + ((scol8 ^ (row & 7)) << 3),
                    dst + s * 4096 + t * 8);
        }
    };
    auto issueB = [&](u16* dst, int h, int k0) {
#pragma unroll
        for (int s = 0; s < 2; s++) {
            int row = h * 128 + s * 64 + srow;
            gload16(B + (size_t)(n0 + row) * 4096 + k0 + ((scol8 ^ (row & 7)) << 3),
                    dst + h * 8192 + s * 4096 + t * 8);
        }
    };

    issueA(lds, 0);
    issueB(lds + 8192, 0, 0);
    issueB(lds + 8192, 1, 0);

    for (int kt = 0; kt < 32; kt++) {
        u16* lA = (kt & 1) ? lds + 24576 : lds;
        u16* lB = lA + 8192;
        u16* pA = (kt & 1) ? lds : lds + 24576;
        u16* pB = pA + 8192;
        const int k0n = (kt + 1) << 6;
        const bool pf = kt < 31;
        asm volatile("" ::: "memory");
        __builtin_amdgcn_s_barrier();
        asm volatile("" ::: "memory");
        if (pf) {
            issueA(pA, k0n);                                  // 6 -> 8
            asm volatile("s_waitcnt vmcnt(2)" ::: "memory");  // kt's 6 landed
        } else {
            asm volatile("s_waitcnt vmcnt(0)" ::: "memory");
        }
        __builtin_amdgcn_s_barrier();
        asm volatile("" ::: "memory");

        bf16x8 af[4], bfr[2];
        int sl = (quad ^ fx) * 8;
#pragma unroll
        for (int i = 0; i < 4; i++)
            af[i] = *(const bf16x8*)&lA[(wm + i * 16 + mf) * 64 + sl];
#pragma unroll
        for (int j = 0; j < 2; j++)
            bfr[j] = *(const bf16x8*)&lB[(wn + j * 16 + mf) * 64 + sl];
        __builtin_amdgcn_s_setprio(1);
#pragma unroll
        for (int i = 0; i < 4; i++)
#pragma unroll
            for (int j = 0; j < 2; j++)
                acc[i][j] = __builtin_amdgcn_mfma_f32_16x16x32_bf16(af[i], bfr[j], acc[i][j], 0, 0, 0);
        __builtin_amdgcn_s_setprio(0);
        if (pf) issueB(pB, 0, k0n);
#pragma unroll
        for (int j = 0; j < 2; j++)
            bfr[j] = *(const bf16x8*)&lB[(wn + (2 + j) * 16 + mf) * 64 + sl];
        __builtin_amdgcn_s_setprio(1);
#pragma unroll
        for (int i = 0; i < 4; i++)
#pragma unroll
            for (int j = 0; j < 2; j++)
                acc[i][2 + j] = __builtin_amdgcn_mfma_f32_16x16x32_bf16(af[i], bfr[j], acc[i][2 + j], 0, 0, 0);
        __builtin_amdgcn_s_setprio(0);
        sl = ((4 + quad) ^ fx) * 8;
        if (pf) issueB(pB, 1, k0n);
#pragma unroll
        for (int i = 0; i < 4; i++)
            af[i] = *(const bf16x8*)&lA[(wm + i * 16 + mf) * 64 + sl];
#pragma unroll
        for (int j = 0; j < 2; j++)
            bfr[j] = *(const bf16x8*)&lB[(wn + j * 16 + mf) * 64 + sl];
        __builtin_amdgcn_s_setprio(1);
#pragma unroll
        for (int i = 0; i < 4; i++)
#pragma unroll
            for (int j = 0; j < 2; j++)
                acc[i][j] = __builtin_amdgcn_mfma_f32_16x16x32_bf16(af[i], bfr[j], acc[i][j], 0, 0, 0);
        __builtin_amdgcn_s_setprio(0);
#pragma unroll
        for (int j = 0; j < 2; j++)
            bfr[j] = *(const bf16x8*)&lB[(wn + (2 + j) * 16 + mf) * 64 + sl];
        __builtin_amdgcn_s_setprio(1);
#pragma unroll
        for (int i = 0; i < 4; i++)
#pragma unroll
            for (int j = 0; j < 2; j++)
                acc[i][2 + j] = __builtin_amdgcn_mfma_f32_16x16x32_bf16(af[i], bfr[j], acc[i][2 + j], 0, 0, 0);
        __builtin_amdgcn_s_setprio(0);
    }

    u16* P = (split == 0 ? QT : KT) + (size_t)b * 2097152;
    __syncthreads();
#pragma unroll
    for (int i = 0; i < 4; i++)
#pragma unroll
        for (int r = 0; r < 4; r++) {
            int row = wm + i * 16 + quad * 4 + r;       // 0..127
            int key = row & 7;
#pragma unroll
            for (int j = 0; j < 4; j++) {
                int col = wn + j * 16 + mf;             // 0..255
                lds[row * 256 + (((col >> 3) ^ key) << 3) + (col & 7)] =
                    f2bf(acc[i][j][r]);
            }
        }
    __syncthreads();
    for (int p = 0; p < 8; p++) {
        int idx = p * 512 + t;
        int row = idx >> 5, chunk = idx & 31;
        uint4 v = *(const uint4*)&lds[row * 256 + ((chunk ^ (row & 7)) << 3)];
        *(uint4*)&P[(size_t)(m0 + row) * 512 + n0 + chunk * 8] = v;
    }
}

// ---------------------------------------------------------------------------
// Reduce partials + softmax normalization: OT_b = (P0 + P1) / rowsum.
// Part has 16 panels per row. grid (1024, nb).
// ---------------------------------------------------------------------------
__global__ __launch_bounds__(256) void k_pv_reduce(const u16* __restrict__ QT,
                                                   const u16* __restrict__ KT,
                                                   const float* __restrict__ Part,
                                                   u16* __restrict__ OT,
                                                   int b0) {
    const int b = b0 + blockIdx.y;
    const int t = threadIdx.x;
    __shared__ float sInv[4];
    if (t < 64) {
        int r = t >> 4, which = t & 15;
        int p = blockIdx.x * 4 + r;
        float v = Part[((size_t)b * 16 + which) * 4096 + p];
        for (int off = 8; off > 0; off >>= 1) v += __shfl_xor(v, off);
        if (which == 0) sInv[r] = 1.f / v;
    }
    __syncthreads();
    const float inv = sInv[t >> 6];
    size_t base = (size_t)b * 2097152;
    size_t i0 = base + ((size_t)blockIdx.x * 256 + t) * 8;
    uint4 a = *(const uint4*)(QT + i0);
    uint4 c = *(const uint4*)(KT + i0);
    uint32_t wa[4] = {a.x, a.y, a.z, a.w};
    uint32_t wc[4] = {c.x, c.y, c.z, c.w};
    uint32_t o[4];
    for (int j = 0; j < 4; j++) {
        float lo = (__uint_as_float(wa[j] << 16) + __uint_as_float(wc[j] << 16)) * inv;
        float hi = (__uint_as_float(wa[j] & 0xFFFF0000u) + __uint_as_float(wc[j] & 0xFFFF0000u)) * inv;
        o[j] = (uint32_t)f2bf(lo) | ((uint32_t)f2bf(hi) << 16);
    }
    *(uint4*)(OT + i0) = make_uint4(o[0], o[1], o[2], o[3]);
}

// ---------------------------------------------------------------------------
// Proj + residual, 256x256 tile, counted-vmcnt fine-interleaved schedule.
// grid (16, 2, 8) = 256 blocks = exactly 1 CU round. M=512 ch (2 m-tiles),
// N=4096 pix (16 n-tiles). Main loop identical to k_qkv template (A=Wp,
// B=OT, K=512). Epilogue: two 128-row halves of f32 LDS-bounce (128x256x4B
// = 128 KiB), 16B-chunk XOR swizzle, vectorized bias+residual store.
// ---------------------------------------------------------------------------
__global__ __launch_bounds__(512, 2) void k_proj(const u16* __restrict__ Wc,
                                                 const u16* __restrict__ OT,
                                                 const u16* __restrict__ Bc,
                                                 const void* __restrict__ x_raw,
                                                 const int* __restrict__ flag,
                                                 void* __restrict__ y_raw) {
    __shared__ __align__(16) u16 lds[65536];   // 128 KiB
    float* smf = (float*)lds;
    int nI, mI, b;
    swz(nI, mI, b);
    const int n0 = nI * 256;   // pixels
    const int m0 = mI * 256;   // channels
    const u16* A = Wc + (size_t)3 * 262144;
    const u16* B = OT + (size_t)b * 2097152;

    const int t = threadIdx.x;
    const int wave = t >> 6, lane = t & 63;
    const int wm = (wave >> 2) * 128, wn = (wave & 3) * 64;   // 2m x 4n
    const int mf = lane & 15, quad = lane >> 4;
    const int fx = mf & 7;
    const int srow = t >> 3;
    const int scol8 = t & 7;

    f32x4 acc[8][4];
#pragma unroll
    for (int i = 0; i < 8; i++)
#pragma unroll
        for (int j = 0; j < 4; j++)
            acc[i][j] = (f32x4){0.f, 0.f, 0.f, 0.f};

    auto issueA = [&](u16* dst, int h, int k0) {
#pragma unroll
        for (int ss = 0; ss < 2; ss++) {
            int row = h * 128 + ss * 64 + srow;
            gload16(A + (size_t)(m0 + row) * 512 + k0 + ((scol8 ^ (row & 7)) << 3),
                    dst + h * 8192 + ss * 4096 + t * 8);
        }
    };
    auto issueB = [&](u16* dst, int h, int k0) {
#pragma unroll
        for (int ss = 0; ss < 2; ss++) {
            int row = h * 128 + ss * 64 + srow;
            gload16(B + (size_t)(n0 + row) * 512 + k0 + ((scol8 ^ (row & 7)) << 3),
                    dst + h * 8192 + ss * 4096 + t * 8);
        }
    };

    issueA(lds, 0, 0); issueA(lds, 1, 0);
    issueB(lds + 16384, 0, 0); issueB(lds + 16384, 1, 0);

    for (int kt = 0; kt < 8; kt++) {
        u16* lA = (kt & 1) ? lds + 32768 : lds;
        u16* lB = lA + 16384;
        u16* pA = (kt & 1) ? lds : lds + 32768;
        u16* pB = pA + 16384;
        const int k0n = (kt + 1) << 6;
        const bool pf = kt < 7;
        asm volatile("" ::: "memory");
        __builtin_amdgcn_s_barrier();
        asm volatile("" ::: "memory");
        if (pf) {
            issueA(pA, 0, k0n);
            asm volatile("s_waitcnt vmcnt(2)" ::: "memory");
        } else {
            asm volatile("s_waitcnt vmcnt(0)" ::: "memory");
        }
        __builtin_amdgcn_s_barrier();
        asm volatile("" ::: "memory");

        bf16x8 af[8], bfr[2];
        int sl = (quad ^ fx) * 8;
#pragma unroll
        for (int i = 0; i < 8; i++)
            af[i] = *(const bf16x8*)&lA[(wm + i * 16 + mf) * 64 + sl];
#pragma unroll
        for (int j = 0; j < 2; j++)
            bfr[j] = *(const bf16x8*)&lB[(wn + j * 16 + mf) * 64 + sl];
        __builtin_amdgcn_s_setprio(1);
#pragma unroll
        for (int i = 0; i < 8; i++)
#pragma unroll
            for (int j = 0; j < 2; j++)
                acc[i][j] = __builtin_amdgcn_mfma_f32_16x16x32_bf16(af[i], bfr[j], acc[i][j], 0, 0, 0);
        __builtin_amdgcn_s_setprio(0);
        if (pf) issueA(pA, 1, k0n);
#pragma unroll
        for (int j = 0; j < 2; j++)
            bfr[j] = *(const bf16x8*)&lB[(wn + (2 + j) * 16 + mf) * 64 + sl];
        __builtin_amdgcn_s_setprio(1);
#pragma unroll
        for (int i = 0; i < 8; i++)
#pragma unroll
            for (int j = 0; j < 2; j++)
                acc[i][2 + j] = __builtin_amdgcn_mfma_f32_16x16x32_bf16(af[i], bfr[j], acc[i][2 + j], 0, 0, 0);
        __builtin_amdgcn_s_setprio(0);
        sl = ((4 + quad) ^ fx) * 8;
        if (pf) issueB(pB, 0, k0n);
#pragma unroll
        for (int i = 0; i < 8; i++)
            af[i] = *(const bf16x8*)&lA[(wm + i * 16 + mf) * 64 + sl];
#pragma unroll
        for (int j = 0; j < 2; j++)
            bfr[j] = *(const bf16x8*)&lB[(wn + j * 16 + mf) * 64 + sl];
        __builtin_amdgcn_s_setprio(1);
#pragma unroll
        for (int i = 0; i < 8; i++)
#pragma unroll
            for (int j = 0; j < 2; j++)
                acc[i][j] = __builtin_amdgcn_mfma_f32_16x16x32_bf16(af[i], bfr[j], acc[i][j], 0, 0, 0);
        __builtin_amdgcn_s_setprio(0);
        if (pf) issueB(pB, 1, k0n);
#pragma unroll
        for (int j = 0; j < 2; j++)
            bfr[j] = *(const bf16x8*)&lB[(wn + (2 + j) * 16 + mf) * 64 + sl];
        __builtin_amdgcn_s_setprio(1);
#pragma unroll
        for (int i = 0; i < 8; i++)
#pragma unroll
            for (int j = 0; j < 2; j++)
                acc[i][2 + j] = __builtin_amdgcn_mfma_f32_16x16x32_bf16(af[i], bfr[j], acc[i][2 + j], 0, 0, 0);
        __builtin_amdgcn_s_setprio(0);
    }

    // ---- epilogue: f32 bounce in two 128-row halves + residual ----
    const int mode = *flag;
    const u16* bp = Bc + 5 * 512;
    size_t bb = (size_t)b * 2097152;
    const int whalf = wave >> 2;
    for (int h = 0; h < 2; h++) {
        __syncthreads();
        if (whalf == h) {
#pragma unroll
            for (int i = 0; i < 8; i++)
#pragma unroll
                for (int r = 0; r < 4; r++) {
                    int row = i * 16 + quad * 4 + r;     // 0..127 (local)
                    int key = row & 7;
#pragma unroll
                    for (int j = 0; j < 4; j++) {
                        int col = wn + j * 16 + mf;      // 0..255
                        smf[row * 256 + (((col >> 2) ^ key) << 2) + (col & 3)] =
                            acc[i][j][r];
                    }
                }
        }
        __syncthreads();
        const int rowbase = m0 + h * 128;
        if (mode) {
            for (int p = 0; p < 16; p++) {
                int idx = p * 512 + t;
                int rowl = idx >> 6, c4 = idx & 63;
                int key = rowl & 7;
                f32x4 v = *(const f32x4*)&smf[rowl * 256 + ((c4 ^ key) << 2)];
                int rowg = rowbase + rowl;
                float bias = bf2f(bp[rowg]);
                size_t o = bb + (size_t)rowg * 4096 + n0 + c4 * 4;
                float4 xv = *(const float4*)((const float*)x_raw + o);
                float4 out = make_float4(v[0] + bias + xv.x, v[1] + bias + xv.y,
                                         v[2] + bias + xv.z, v[3] + bias + xv.w);
                *(float4*)((float*)y_raw + o) = out;
            }
        } else {
            for (int p = 0; p < 8; p++) {
                int idx = p * 512 + t;
                int rowl = idx >> 5, cp = idx & 31;
                int key = rowl & 7;
                f32x4 v0 = *(const f32x4*)&smf[rowl * 256 + (((2 * cp) ^ key) << 2)];
                f32x4 v1 = *(const f32x4*)&smf[rowl * 256 + (((2 * cp + 1) ^ key) << 2)];
                int rowg = rowbase + rowl;
                float bias = bf2f(bp[rowg]);
                size_t o = bb + (size_t)rowg * 4096 + n0 + cp * 8;
                uint4 xv = *(const uint4*)((const u16*)x_raw + o);
                uint32_t xw[4] = {xv.x, xv.y, xv.z, xv.w};
                float vals[8] = {v0[0], v0[1], v0[2], v0[3],
                                 v1[0], v1[1], v1[2], v1[3]};
                uint32_t ow[4];
                for (int q2 = 0; q2 < 4; q2++) {
                    float lo = __uint_as_float(xw[q2] << 16) + vals[2 * q2] + bias;
                    float hi = __uint_as_float(xw[q2] & 0xFFFF0000u) + vals[2 * q2 + 1] + bias;
                    ow[q2] = (uint32_t)f2bf(lo) | ((uint32_t)f2bf(hi) << 16);
                }
                *(uint4*)((u16*)y_raw + o) = make_uint4(ow[0], ow[1], ow[2], ow[3]);
            }
        }
    }
}

// ---------------------------------------------------------------------------
extern "C" void kernel_launch(void* const* d_in, const int* in_sizes, int n_in,
                              void* d_out, int out_size, void* d_ws, size_t ws_size,
                              hipStream_t stream) {
    (void)in_sizes; (void)n_in; (void)out_size;
    const void* x  = d_in[0];
    const void* gw = d_in[1];
    const void* gb = d_in[2];
    const void* wq = d_in[3];
    const void* bq = d_in[4];
    const void* wk = d_in[5];
    const void* bk = d_in[6];
    const void* wv = d_in[7];
    const void* bv = d_in[8];
    const void* wp = d_in[9];
    const void* bp = d_in[10];

    u16* ws16 = (u16*)d_ws;
    int* flag = (int*)d_ws;                 // u16 elems 0..15
    float* Sc = (float*)(ws16 + 16);        // 4096 f32
    float* Sh = Sc + 4096;                  // 4096 f32
    u16* Wc = ws16 + 16 + 16384;            // 1048576
    u16* Bc = Wc + 1048576;                 // 4096
    u16* HT = Bc + 4096;                    // 16777216 (S slot 0 after qkv)
    u16* QT = HT + 16777216;
    u16* KT = QT + 16777216;
    u16* V  = KT + 16777216;
    u16* OT = V  + 16777216;
    float* Part = (float*)(OT + 16777216);  // reserved 4 MB (uses 2 MB)
    u16* Tail = (u16*)(Part + 1048576);     // S slots 1..nb-1
    const size_t base_elems = (size_t)(Tail - ws16);

    int nb = 1;
    for (int cand = 8; cand >= 2; cand >>= 1) {
        size_t need = 2ull * (base_elems + (size_t)(cand - 1) * 16777216ull);
        if (ws_size >= need) { nb = cand; break; }
    }

    k_detect<<<1, 256, 0, stream>>>((const u16*)x, flag);
    k_cvt_wb<<<4108, 256, 0, stream>>>(wq, wk, wv, wp, gw, gb, bq, bk, bv, bp,
                                       flag, Wc, Bc);
    k_gn_stats<<<256, 256, 0, stream>>>(x, Bc, flag, Sc, Sh);
    k_gn_apply<<<dim3(64, 8), 256, 0, stream>>>(x, flag, Sc, Sh, HT);
    k_qkv<<<dim3(32, 24), 512, 0, stream>>>(HT, Wc, Bc, QT, KT, V);
    for (int b0 = 0; b0 < 8; b0 += nb) {
        k_scores<<<dim3(16, 16, nb), 512, 0, stream>>>(QT, KT, HT, Tail, Part, b0);
        k_pv_split<<<dim3(2, 32, 2 * nb), 512, 0, stream>>>(HT, Tail, V, QT, KT, b0);
        k_pv_reduce<<<dim3(1024, nb), 256, 0, stream>>>(QT, KT, Part, OT, b0);
    }
    k_proj<<<dim3(16, 2, 8), 512, 0, stream>>>(Wc, OT, Bc, x, flag, d_out);
}

// Round 13
// 683.404 us; speedup vs baseline: 1.0988x; 1.0988x over previous
//
#include <hip/hip_runtime.h>
#include <cstdint>

typedef unsigned short u16;
typedef __bf16 bf16x8 __attribute__((ext_vector_type(8)));
typedef float f32x4 __attribute__((ext_vector_type(4)));

__device__ __forceinline__ u16 f2bf(float f) {
    uint32_t u = __float_as_uint(f);
    u += 0x7FFFu + ((u >> 16) & 1u);
    return (u16)(u >> 16);
}
__device__ __forceinline__ float bf2f(u16 v) {
    return __uint_as_float((uint32_t)v << 16);
}

// async global->LDS, 16B per lane (m97: emits global_load_lds_dwordx4)
__device__ __forceinline__ void gload16(const u16* g, u16* l) {
    __builtin_amdgcn_global_load_lds(
        (const __attribute__((address_space(1))) uint32_t*)g,
        (__attribute__((address_space(3))) uint32_t*)l, 16, 0, 0);
}

// XCD-aware work swizzle (bijective for these grids).
__device__ __forceinline__ void swz(int& n_idx, int& m_idx, int& z_idx) {
    const int nx = gridDim.x, ny = gridDim.y;
    int lid = blockIdx.x + nx * (blockIdx.y + ny * blockIdx.z);
    int g = lid & 7, h = lid >> 3;
    n_idx = h % nx;
    int pair = (h / nx) * 8 + g;
    m_idx = pair % ny;
    z_idx = pair / ny;
}

// ---------------------------------------------------------------------------
// Dtype detect (1=fp32 storage, 0=bf16).
// ---------------------------------------------------------------------------
__global__ __launch_bounds__(256) void k_detect(const u16* __restrict__ x,
                                                int* __restrict__ flag) {
    const int t = threadIdx.x;
    uint32_t mx = 0;
    for (int i = 0; i < 256; i++) {
        uint32_t v = (uint32_t)x[i * 256 + t] & 0x7FFFu;
        mx = mx > v ? mx : v;
    }
    for (int off = 32; off > 0; off >>= 1) {
        uint32_t o = (uint32_t)__shfl_xor((int)mx, off);
        mx = mx > o ? mx : o;
    }
    __shared__ uint32_t r[4];
    if ((t & 63) == 0) r[t >> 6] = mx;
    __syncthreads();
    if (t == 0) {
        uint32_t a = r[0] > r[1] ? r[0] : r[1];
        uint32_t b = r[2] > r[3] ? r[2] : r[3];
        mx = a > b ? a : b;
        *flag = (mx > 0x5000u) ? 1 : 0;
    }
}

// ---------------------------------------------------------------------------
// Canonicalize weights/vectors into bf16 (Wc: wq|wk|wv|wp, Bc: gw|gb|bq|bk|bv|bp)
// ---------------------------------------------------------------------------
__global__ __launch_bounds__(256) void k_cvt_wb(const void* wq, const void* wk,
                                                const void* wv, const void* wp,
                                                const void* gw, const void* gb,
                                                const void* bq, const void* bk,
                                                const void* bv, const void* bp,
                                                const int* __restrict__ flag,
                                                u16* __restrict__ Wc,
                                                u16* __restrict__ Bc) {
    const int mode = *flag;
    int i = blockIdx.x * 256 + threadIdx.x;
    if (i >= 1048576 + 3072) return;
    const void* src;
    u16* dst;
    int off;
    if (i < 1048576) {
        int which = i >> 18;
        off = i & 262143;
        src = which == 0 ? wq : which == 1 ? wk : which == 2 ? wv : wp;
        dst = Wc + i;
    } else {
        int j = i - 1048576;
        int which = j >> 9;
        off = j & 511;
        src = which == 0 ? gw : which == 1 ? gb : which == 2 ? bq
            : which == 3 ? bk : which == 4 ? bv : bp;
        dst = Bc + j;
    }
    *dst = mode ? f2bf(((const float*)src)[off]) : ((const u16*)src)[off];
}

// ---------------------------------------------------------------------------
// GN stats: one block per (b,g); writes per-channel scale/shift (fp32).
// ---------------------------------------------------------------------------
__global__ __launch_bounds__(256) void k_gn_stats(const void* __restrict__ x_raw,
                                                  const u16* __restrict__ Bc,
                                                  const int* __restrict__ flag,
                                                  float* __restrict__ Sc,
                                                  float* __restrict__ Sh) {
    const int b = blockIdx.x >> 5, g = blockIdx.x & 31;
    const int mode = *flag;
    const int t = threadIdx.x;
    const int wave = t >> 6, lane = t & 63;
    float s = 0.f, ss = 0.f;
    if (mode) {
        const float4* xb = (const float4*)((const float*)x_raw +
                                           ((size_t)b * 512 + g * 16) * 4096);
        for (int it = 0; it < 64; it++) {
            float4 v = xb[it * 256 + t];
            s += v.x + v.y + v.z + v.w;
            ss += v.x * v.x + v.y * v.y + v.z * v.z + v.w * v.w;
        }
    } else {
        const uint4* xb = (const uint4*)((const u16*)x_raw +
                                         ((size_t)b * 512 + g * 16) * 4096);
        for (int it = 0; it < 32; it++) {
            uint4 v = xb[it * 256 + t];
            uint32_t w[4] = {v.x, v.y, v.z, v.w};
            for (int j = 0; j < 4; j++) {
                float a = __uint_as_float(w[j] << 16);
                float c = __uint_as_float(w[j] & 0xFFFF0000u);
                s += a + c;
                ss += a * a + c * c;
            }
        }
    }
    for (int off = 32; off > 0; off >>= 1) {
        s += __shfl_xor(s, off);
        ss += __shfl_xor(ss, off);
    }
    __shared__ float rs[4], rss[4];
    if (lane == 0) { rs[wave] = s; rss[wave] = ss; }
    __syncthreads();
    s = rs[0] + rs[1] + rs[2] + rs[3];
    ss = rss[0] + rss[1] + rss[2] + rss[3];
    const float mean = s * (1.f / 65536.f);
    const float var = ss * (1.f / 65536.f) - mean * mean;
    const float rstd = rsqrtf(var + 1e-6f);
    if (t < 16) {
        int c = g * 16 + t;
        float w = bf2f(Bc[c]);
        Sc[b * 512 + c] = rstd * w;
        Sh[b * 512 + c] = bf2f(Bc[512 + c]) - mean * rstd * w;
    }
}

// ---------------------------------------------------------------------------
// GN apply + transpose -> HT[b][p][c] (contiguous 1KB rows). grid (64, 8).
// ---------------------------------------------------------------------------
#define TPAD 520
__global__ __launch_bounds__(256) void k_gn_apply(const void* __restrict__ x_raw,
                                                  const int* __restrict__ flag,
                                                  const float* __restrict__ Sc,
                                                  const float* __restrict__ Sh,
                                                  u16* __restrict__ HT) {
    __shared__ u16 tile[64 * TPAD];
    __shared__ float sSc[512], sSh[512];
    const int b = blockIdx.y;
    const int p0 = blockIdx.x * 64;
    const int mode = *flag;
    const int t = threadIdx.x;
    sSc[t] = Sc[b * 512 + t]; sSc[t + 256] = Sc[b * 512 + t + 256];
    sSh[t] = Sh[b * 512 + t]; sSh[t + 256] = Sh[b * 512 + t + 256];
    __syncthreads();
    for (int it = 0; it < 16; it++) {
        int li = it * 256 + t;
        int c = li >> 3;
        int pj = (li & 7) * 8;
        float v[8];
        if (mode) {
            const float* xr = (const float*)x_raw + ((size_t)b * 512 + c) * 4096 + p0 + pj;
            float4 a = *(const float4*)xr;
            float4 d = *(const float4*)(xr + 4);
            v[0] = a.x; v[1] = a.y; v[2] = a.z; v[3] = a.w;
            v[4] = d.x; v[5] = d.y; v[6] = d.z; v[7] = d.w;
        } else {
            const u16* xr = (const u16*)x_raw + ((size_t)b * 512 + c) * 4096 + p0 + pj;
            uint4 a = *(const uint4*)xr;
            uint32_t w[4] = {a.x, a.y, a.z, a.w};
            for (int j = 0; j < 4; j++) {
                v[2 * j] = __uint_as_float(w[j] << 16);
                v[2 * j + 1] = __uint_as_float(w[j] & 0xFFFF0000u);
            }
        }
        float sc = sSc[c], sh = sSh[c];
        for (int k = 0; k < 8; k++)
            tile[(pj + k) * TPAD + c] = f2bf(v[k] * sc + sh);
    }
    __syncthreads();
    u16* H = HT + (size_t)b * 2097152 + (size_t)p0 * 512;
    for (int it = 0; it < 16; it++) {
        int ch = it * 256 + t;
        int pp = ch >> 6;
        int cc = (ch & 63) * 8;
        *(uint4*)&H[(size_t)pp * 512 + cc] = *(const uint4*)&tile[pp * TPAD + cc];
    }
}

// ---------------------------------------------------------------------------
// 128x128 tile GEMM core (R2-verified): BK=64, 256 thr, single-buffer,
// plain __syncthreads schedule. lA/lB: 8192 u16 each. K multiple of 64.
// Kept for k_proj: its cost is the 176 MB epilogue stream, which overlaps
// across 5 blocks/CU here (256^2/128KiB template serializes it: R12 +59us).
// ---------------------------------------------------------------------------
__device__ __forceinline__ void gemm_core(const u16* __restrict__ A,
                                          const u16* __restrict__ BT,
                                          int lda, int ldb, int K,
                                          int m0, int n0,
                                          u16* lA, u16* lB,
                                          f32x4 (&acc)[4][4]) {
    const int t = threadIdx.x;
    const int wave = t >> 6, lane = t & 63;
    const int wm = (wave >> 1) * 64, wn = (wave & 1) * 64;
    const int mf = lane & 15, quad = lane >> 4;
    const int srow = t >> 3;                        // 0..31
    const int scol = (((t & 7) ^ (srow & 7)) * 8);  // XOR-swizzled source col
    const u16* Ap = A + (size_t)(m0 + srow) * lda + scol;
    const u16* Bp = BT + (size_t)(n0 + srow) * ldb + scol;
    u16* lAd = &lA[t * 8];
    u16* lBd = &lB[t * 8];
    const int fx = mf & 7;

    for (int i = 0; i < 4; i++)
        for (int j = 0; j < 4; j++)
            acc[i][j] = (f32x4){0.f, 0.f, 0.f, 0.f};

    for (int k0 = 0; k0 < K; k0 += 64) {
        __syncthreads();
        gload16(Ap + k0, lAd);
        gload16(Ap + k0 + (size_t)32 * lda, lAd + 2048);
        gload16(Ap + k0 + (size_t)64 * lda, lAd + 4096);
        gload16(Ap + k0 + (size_t)96 * lda, lAd + 6144);
        gload16(Bp + k0, lBd);
        gload16(Bp + k0 + (size_t)32 * ldb, lBd + 2048);
        gload16(Bp + k0 + (size_t)64 * ldb, lBd + 4096);
        gload16(Bp + k0 + (size_t)96 * ldb, lBd + 6144);
        __syncthreads();
        for (int ks = 0; ks < 2; ks++) {
            bf16x8 af[4], bfr[4];
            const int sl = ((ks * 4 + quad) ^ fx) * 8;
            for (int i = 0; i < 4; i++)
                af[i] = *(const bf16x8*)&lA[(wm + i * 16 + mf) * 64 + sl];
            for (int j = 0; j < 4; j++)
                bfr[j] = *(const bf16x8*)&lB[(wn + j * 16 + mf) * 64 + sl];
            for (int i = 0; i < 4; i++)
                for (int j = 0; j < 4; j++)
                    acc[i][j] = __builtin_amdgcn_mfma_f32_16x16x32_bf16(af[i], bfr[j], acc[i][j], 0, 0, 0);
        }
    }
}

// ---------------------------------------------------------------------------
// QKV, 256x256 tile, counted-vmcnt fine-interleaved schedule.
// grid (32, 24). 768 blocks = 3 full CU rounds.
// ---------------------------------------------------------------------------
__global__ __launch_bounds__(512, 2) void k_qkv(const u16* __restrict__ HT,
                                                const u16* __restrict__ Wc,
                                                const u16* __restrict__ Bc,
                                                u16* __restrict__ QT,
                                                u16* __restrict__ KT,
                                                u16* __restrict__ V) {
    __shared__ __align__(16) u16 lds[65536];   // 128 KiB: A0|B0|A1|B1 @16384
    int xI, bs, dz;
    swz(xI, bs, dz);
    const int b = bs / 3, s = bs % 3;
    const u16* Bb = Bc + 1024 + s * 512;
    int m0, n0, ldo, bias_by_row;
    const u16 *A, *B;
    u16* O;
    if (s < 2) {
        m0 = (xI >> 1) * 256; n0 = (xI & 1) * 256;
        A = HT + (size_t)b * 2097152; B = Wc + (size_t)s * 262144;
        O = (s == 0 ? QT : KT) + (size_t)b * 2097152; ldo = 512; bias_by_row = 0;
    } else {
        m0 = (xI & 1) * 256; n0 = (xI >> 1) * 256;
        A = Wc + (size_t)2 * 262144; B = HT + (size_t)b * 2097152;
        O = V + (size_t)b * 2097152; ldo = 4096; bias_by_row = 1;
    }

    const int t = threadIdx.x;
    const int wave = t >> 6, lane = t & 63;
    const int wm = (wave >> 2) * 128, wn = (wave & 3) * 64;   // 2m x 4n
    const int mf = lane & 15, quad = lane >> 4;
    const int fx = mf & 7;
    const int srow = t >> 3;      // 0..63 per sweep
    const int scol8 = t & 7;

    f32x4 acc[8][4];
#pragma unroll
    for (int i = 0; i < 8; i++)
#pragma unroll
        for (int j = 0; j < 4; j++)
            acc[i][j] = (f32x4){0.f, 0.f, 0.f, 0.f};

    auto issueA = [&](u16* dst, int h, int k0) {
#pragma unroll
        for (int ss = 0; ss < 2; ss++) {
            int row = h * 128 + ss * 64 + srow;
            gload16(A + (size_t)(m0 + row) * 512 + k0 + ((scol8 ^ (row & 7)) << 3),
                    dst + h * 8192 + ss * 4096 + t * 8);
        }
    };
    auto issueB = [&](u16* dst, int h, int k0) {
#pragma unroll
        for (int ss = 0; ss < 2; ss++) {
            int row = h * 128 + ss * 64 + srow;
            gload16(B + (size_t)(n0 + row) * 512 + k0 + ((scol8 ^ (row & 7)) << 3),
                    dst + h * 8192 + ss * 4096 + t * 8);
        }
    };

    issueA(lds, 0, 0); issueA(lds, 1, 0);
    issueB(lds + 16384, 0, 0); issueB(lds + 16384, 1, 0);

    for (int kt = 0; kt < 8; kt++) {
        u16* lA = (kt & 1) ? lds + 32768 : lds;
        u16* lB = lA + 16384;
        u16* pA = (kt & 1) ? lds : lds + 32768;
        u16* pB = pA + 16384;
        const int k0n = (kt + 1) << 6;
        const bool pf = kt < 7;
        asm volatile("" ::: "memory");
        __builtin_amdgcn_s_barrier();
        asm volatile("" ::: "memory");
        if (pf) {
            issueA(pA, 0, k0n);
            asm volatile("s_waitcnt vmcnt(2)" ::: "memory");
        } else {
            asm volatile("s_waitcnt vmcnt(0)" ::: "memory");
        }
        __builtin_amdgcn_s_barrier();
        asm volatile("" ::: "memory");

        bf16x8 af[8], bfr[2];
        int sl = (quad ^ fx) * 8;
#pragma unroll
        for (int i = 0; i < 8; i++)
            af[i] = *(const bf16x8*)&lA[(wm + i * 16 + mf) * 64 + sl];
#pragma unroll
        for (int j = 0; j < 2; j++)
            bfr[j] = *(const bf16x8*)&lB[(wn + j * 16 + mf) * 64 + sl];
        __builtin_amdgcn_s_setprio(1);
#pragma unroll
        for (int i = 0; i < 8; i++)
#pragma unroll
            for (int j = 0; j < 2; j++)
                acc[i][j] = __builtin_amdgcn_mfma_f32_16x16x32_bf16(af[i], bfr[j], acc[i][j], 0, 0, 0);
        __builtin_amdgcn_s_setprio(0);
        if (pf) issueA(pA, 1, k0n);
#pragma unroll
        for (int j = 0; j < 2; j++)
            bfr[j] = *(const bf16x8*)&lB[(wn + (2 + j) * 16 + mf) * 64 + sl];
        __builtin_amdgcn_s_setprio(1);
#pragma unroll
        for (int i = 0; i < 8; i++)
#pragma unroll
            for (int j = 0; j < 2; j++)
                acc[i][2 + j] = __builtin_amdgcn_mfma_f32_16x16x32_bf16(af[i], bfr[j], acc[i][2 + j], 0, 0, 0);
        __builtin_amdgcn_s_setprio(0);
        sl = ((4 + quad) ^ fx) * 8;
        if (pf) issueB(pB, 0, k0n);
#pragma unroll
        for (int i = 0; i < 8; i++)
            af[i] = *(const bf16x8*)&lA[(wm + i * 16 + mf) * 64 + sl];
#pragma unroll
        for (int j = 0; j < 2; j++)
            bfr[j] = *(const bf16x8*)&lB[(wn + j * 16 + mf) * 64 + sl];
        __builtin_amdgcn_s_setprio(1);
#pragma unroll
        for (int i = 0; i < 8; i++)
#pragma unroll
            for (int j = 0; j < 2; j++)
                acc[i][j] = __builtin_amdgcn_mfma_f32_16x16x32_bf16(af[i], bfr[j], acc[i][j], 0, 0, 0);
        __builtin_amdgcn_s_setprio(0);
        if (pf) issueB(pB, 1, k0n);
#pragma unroll
        for (int j = 0; j < 2; j++)
            bfr[j] = *(const bf16x8*)&lB[(wn + (2 + j) * 16 + mf) * 64 + sl];
        __builtin_amdgcn_s_setprio(1);
#pragma unroll
        for (int i = 0; i < 8; i++)
#pragma unroll
            for (int j = 0; j < 2; j++)
                acc[i][2 + j] = __builtin_amdgcn_mfma_f32_16x16x32_bf16(af[i], bfr[j], acc[i][2 + j], 0, 0, 0);
        __builtin_amdgcn_s_setprio(0);
    }

    // ---- epilogue: bias + full-tile bounce + coalesced store ----
    __syncthreads();
#pragma unroll
    for (int i = 0; i < 8; i++)
#pragma unroll
        for (int r = 0; r < 4; r++) {
            int row = wm + i * 16 + quad * 4 + r;
            int key = row & 7;
            float brow = bias_by_row ? bf2f(Bb[m0 + row]) : 0.f;
#pragma unroll
            for (int j = 0; j < 4; j++) {
                int col = wn + j * 16 + mf;
                float bias = bias_by_row ? brow : bf2f(Bb[n0 + col]);
                lds[row * 256 + (((col >> 3) ^ key) << 3) + (col & 7)] =
                    f2bf(acc[i][j][r] + bias);
            }
        }
    __syncthreads();
    for (int p = 0; p < 16; p++) {
        int idx = p * 512 + t;
        int row = idx >> 5, chunk = idx & 31;
        uint4 v = *(const uint4*)&lds[row * 256 + ((chunk ^ (row & 7)) << 3)];
        *(uint4*)&O[(size_t)(m0 + row) * ldo + n0 + chunk * 8] = v;
    }
}

// ---------------------------------------------------------------------------
// Local-batch S pointer: l==0 -> HT region, else tail + (l-1)*16M.
// ---------------------------------------------------------------------------
__device__ __forceinline__ u16* s_ptr(u16* S_ht, u16* S_tail, int l) {
    return l == 0 ? S_ht : S_tail + (size_t)(l - 1) * 16777216;
}

// ---------------------------------------------------------------------------
// Scores, 256x256 tile, 8-wave counted-vmcnt fine-interleaved schedule
// (R9-verified). grid (16,16,nb), 512 thr.
// ---------------------------------------------------------------------------
__global__ __launch_bounds__(512, 2) void k_scores(const u16* __restrict__ QT,
                                                   const u16* __restrict__ KT,
                                                   u16* __restrict__ S_ht,
                                                   u16* __restrict__ S_tail,
                                                   float* __restrict__ Part,
                                                   int b0) {
    __shared__ __align__(16) u16 lds[65536];   // 128 KiB: A0|B0|A1|B1 @16384
    int nI, mI, l;
    swz(nI, mI, l);
    const int n0 = nI * 256;
    const int m0 = mI * 256;
    const int b = b0 + l;
    const u16* Aq = QT + (size_t)b * 2097152;
    const u16* Bk = KT + (size_t)b * 2097152;

    const int t = threadIdx.x;
    const int wave = t >> 6, lane = t & 63;
    const int wm = (wave >> 2) * 128, wn = (wave & 3) * 64;   // 2m x 4n
    const int mf = lane & 15, quad = lane >> 4;
    const int fx = mf & 7;
    const int srow = t >> 3;      // 0..63 per sweep
    const int scol8 = t & 7;

    f32x4 acc[8][4];
#pragma unroll
    for (int i = 0; i < 8; i++)
#pragma unroll
        for (int j = 0; j < 4; j++)
            acc[i][j] = (f32x4){0.f, 0.f, 0.f, 0.f};

    auto issueA = [&](u16* dst, int h, int k0) {
#pragma unroll
        for (int s = 0; s < 2; s++) {
            int row = h * 128 + s * 64 + srow;
            gload16(Aq + (size_t)(m0 + row) * 512 + k0 + ((scol8 ^ (row & 7)) << 3),
                    dst + h * 8192 + s * 4096 + t * 8);
        }
    };
    auto issueB = [&](u16* dst, int h, int k0) {
#pragma unroll
        for (int s = 0; s < 2; s++) {
            int row = h * 128 + s * 64 + srow;
            gload16(Bk + (size_t)(n0 + row) * 512 + k0 + ((scol8 ^ (row & 7)) << 3),
                    dst + h * 8192 + s * 4096 + t * 8);
        }
    };

    issueA(lds, 0, 0); issueA(lds, 1, 0);
    issueB(lds + 16384, 0, 0); issueB(lds + 16384, 1, 0);

    for (int kt = 0; kt < 8; kt++) {
        u16* lA = (kt & 1) ? lds + 32768 : lds;
        u16* lB = lA + 16384;
        u16* pA = (kt & 1) ? lds : lds + 32768;
        u16* pB = pA + 16384;
        const int k0n = (kt + 1) << 6;
        const bool pf = kt < 7;
        asm volatile("" ::: "memory");
        __builtin_amdgcn_s_barrier();
        asm volatile("" ::: "memory");
        if (pf) {
            issueA(pA, 0, k0n);
            asm volatile("s_waitcnt vmcnt(2)" ::: "memory");
        } else {
            asm volatile("s_waitcnt vmcnt(0)" ::: "memory");
        }
        __builtin_amdgcn_s_barrier();
        asm volatile("" ::: "memory");

        bf16x8 af[8], bfr[2];
        int sl = (quad ^ fx) * 8;
#pragma unroll
        for (int i = 0; i < 8; i++)
            af[i] = *(const bf16x8*)&lA[(wm + i * 16 + mf) * 64 + sl];
#pragma unroll
        for (int j = 0; j < 2; j++)
            bfr[j] = *(const bf16x8*)&lB[(wn + j * 16 + mf) * 64 + sl];
        __builtin_amdgcn_s_setprio(1);
#pragma unroll
        for (int i = 0; i < 8; i++)
#pragma unroll
            for (int j = 0; j < 2; j++)
                acc[i][j] = __builtin_amdgcn_mfma_f32_16x16x32_bf16(af[i], bfr[j], acc[i][j], 0, 0, 0);
        __builtin_amdgcn_s_setprio(0);
        if (pf) issueA(pA, 1, k0n);
#pragma unroll
        for (int j = 0; j < 2; j++)
            bfr[j] = *(const bf16x8*)&lB[(wn + (2 + j) * 16 + mf) * 64 + sl];
        __builtin_amdgcn_s_setprio(1);
#pragma unroll
        for (int i = 0; i < 8; i++)
#pragma unroll
            for (int j = 0; j < 2; j++)
                acc[i][2 + j] = __builtin_amdgcn_mfma_f32_16x16x32_bf16(af[i], bfr[j], acc[i][2 + j], 0, 0, 0);
        __builtin_amdgcn_s_setprio(0);
        sl = ((4 + quad) ^ fx) * 8;
        if (pf) issueB(pB, 0, k0n);
#pragma unroll
        for (int i = 0; i < 8; i++)
            af[i] = *(const bf16x8*)&lA[(wm + i * 16 + mf) * 64 + sl];
#pragma unroll
        for (int j = 0; j < 2; j++)
            bfr[j] = *(const bf16x8*)&lB[(wn + j * 16 + mf) * 64 + sl];
        __builtin_amdgcn_s_setprio(1);
#pragma unroll
        for (int i = 0; i < 8; i++)
#pragma unroll
            for (int j = 0; j < 2; j++)
                acc[i][j] = __builtin_amdgcn_mfma_f32_16x16x32_bf16(af[i], bfr[j], acc[i][j], 0, 0, 0);
        __builtin_amdgcn_s_setprio(0);
        if (pf) issueB(pB, 1, k0n);
#pragma unroll
        for (int j = 0; j < 2; j++)
            bfr[j] = *(const bf16x8*)&lB[(wn + (2 + j) * 16 + mf) * 64 + sl];
        __builtin_amdgcn_s_setprio(1);
#pragma unroll
        for (int i = 0; i < 8; i++)
#pragma unroll
            for (int j = 0; j < 2; j++)
                acc[i][2 + j] = __builtin_amdgcn_mfma_f32_16x16x32_bf16(af[i], bfr[j], acc[i][2 + j], 0, 0, 0);
        __builtin_amdgcn_s_setprio(0);
    }

    const float scale = 0.04419417382415922f;
    __syncthreads();
#pragma unroll
    for (int i = 0; i < 8; i++)
#pragma unroll
        for (int r = 0; r < 4; r++) {
            int row = wm + i * 16 + quad * 4 + r;
            int key = row & 7;
#pragma unroll
            for (int j = 0; j < 4; j++) {
                int col = wn + j * 16 + mf;
                lds[row * 256 + (((col >> 3) ^ key) << 3) + (col & 7)] =
                    f2bf(__expf(acc[i][j][r] * scale));
            }
        }
    __syncthreads();
    u16* Sb = s_ptr(S_ht, S_tail, l);
    float* pr = Part + ((size_t)b * 16 + nI) * 4096 + m0;
    for (int p = 0; p < 16; p++) {
        int idx = p * 512 + t;
        int row = idx >> 5, chunk = idx & 31;
        uint4 v = *(const uint4*)&lds[row * 256 + ((chunk ^ (row & 7)) << 3)];
        uint32_t w[4] = {v.x, v.y, v.z, v.w};
        float s = 0.f;
        for (int q2 = 0; q2 < 4; q2++)
            s += __uint_as_float(w[q2] << 16) + __uint_as_float(w[q2] & 0xFFFF0000u);
        for (int off = 16; off > 0; off >>= 1) s += __shfl_xor(s, off);
        if ((lane & 31) == 0) pr[row] = s;
        *(uint4*)&Sb[(size_t)(m0 + row) * 4096 + n0 + chunk * 8] = v;
    }
}

// ---------------------------------------------------------------------------
// PV split-K=2, 128x256 tile, 8-wave counted-vmcnt fine-interleaved schedule
// (R10-verified). grid (2, 32, 2*nb) = 256 blocks/launch.
// ---------------------------------------------------------------------------
__global__ __launch_bounds__(512, 2) void k_pv_split(u16* __restrict__ S_ht,
                                                     u16* __restrict__ S_tail,
                                                     const u16* __restrict__ V,
                                                     u16* __restrict__ QT,
                                                     u16* __restrict__ KT,
                                                     int b0) {
    __shared__ __align__(16) u16 lds[49152];
    int nI, mI, zI;
    swz(nI, mI, zI);
    const int n0 = nI * 256;
    const int m0 = mI * 128;
    const int l = zI >> 1, split = zI & 1, b = b0 + l;
    const u16* A = s_ptr(S_ht, S_tail, l) + split * 2048;
    const u16* B = V + (size_t)b * 2097152 + split * 2048;

    const int t = threadIdx.x;
    const int wave = t >> 6, lane = t & 63;
    const int wm = (wave >> 2) * 64, wn = (wave & 3) * 64;   // 2m x 4n
    const int mf = lane & 15, quad = lane >> 4;
    const int fx = mf & 7;
    const int srow = t >> 3;      // 0..63
    const int scol8 = t & 7;

    f32x4 acc[4][4];
#pragma unroll
    for (int i = 0; i < 4; i++)
#pragma unroll
        for (int j = 0; j < 4; j++)
            acc[i][j] = (f32x4){0.f, 0.f, 0.f, 0.f};

    auto issueA = [&](u16* dst, int k0) {
#pragma unroll
        for (int s = 0; s < 2; s++) {
            int row = s * 64 + srow;
            gload16(A + (size_t)(m0 + row) * 4096 + k0 + ((scol8 ^ (row & 7)) << 3),
                    dst + s * 4096 + t * 8);
        }
    };
    auto issueB = [&](u16* dst, int h, int k0) {
#pragma unroll
        for (int s = 0; s < 2; s++) {
            int row = h * 128 + s * 64 + srow;
            gload16(B + (size_t)(n0 + row) * 4096 + k0 + ((scol8 ^ (row & 7)) << 3),
                    dst + h * 8192 + s * 4096 + t * 8);
        }
    };

    issueA(lds, 0);
    issueB(lds + 8192, 0, 0);
    issueB(lds + 8192, 1, 0);

    for (int kt = 0; kt < 32; kt++) {
        u16* lA = (kt & 1) ? lds + 24576 : lds;
        u16* lB = lA + 8192;
        u16* pA = (kt & 1) ? lds : lds + 24576;
        u16* pB = pA + 8192;
        const int k0n = (kt + 1) << 6;
        const bool pf = kt < 31;
        asm volatile("" ::: "memory");
        __builtin_amdgcn_s_barrier();
        asm volatile("" ::: "memory");
        if (pf) {
            issueA(pA, k0n);                                  // 6 -> 8
            asm volatile("s_waitcnt vmcnt(2)" ::: "memory");  // kt's 6 landed
        } else {
            asm volatile("s_waitcnt vmcnt(0)" ::: "memory");
        }
        __builtin_amdgcn_s_barrier();
        asm volatile("" ::: "memory");

        bf16x8 af[4], bfr[2];
        int sl = (quad ^ fx) * 8;
#pragma unroll
        for (int i = 0; i < 4; i++)
            af[i] = *(const bf16x8*)&lA[(wm + i * 16 + mf) * 64 + sl];
#pragma unroll
        for (int j = 0; j < 2; j++)
            bfr[j] = *(const bf16x8*)&lB[(wn + j * 16 + mf) * 64 + sl];
        __builtin_amdgcn_s_setprio(1);
#pragma unroll
        for (int i = 0; i < 4; i++)
#pragma unroll
            for (int j = 0; j < 2; j++)
                acc[i][j] = __builtin_amdgcn_mfma_f32_16x16x32_bf16(af[i], bfr[j], acc[i][j], 0, 0, 0);
        __builtin_amdgcn_s_setprio(0);
        if (pf) issueB(pB, 0, k0n);
#pragma unroll
        for (int j = 0; j < 2; j++)
            bfr[j] = *(const bf16x8*)&lB[(wn + (2 + j) * 16 + mf) * 64 + sl];
        __builtin_amdgcn_s_setprio(1);
#pragma unroll
        for (int i = 0; i < 4; i++)
#pragma unroll
            for (int j = 0; j < 2; j++)
                acc[i][2 + j] = __builtin_amdgcn_mfma_f32_16x16x32_bf16(af[i], bfr[j], acc[i][2 + j], 0, 0, 0);
        __builtin_amdgcn_s_setprio(0);
        sl = ((4 + quad) ^ fx) * 8;
        if (pf) issueB(pB, 1, k0n);
#pragma unroll
        for (int i = 0; i < 4; i++)
            af[i] = *(const bf16x8*)&lA[(wm + i * 16 + mf) * 64 + sl];
#pragma unroll
        for (int j = 0; j < 2; j++)
            bfr[j] = *(const bf16x8*)&lB[(wn + j * 16 + mf) * 64 + sl];
        __builtin_amdgcn_s_setprio(1);
#pragma unroll
        for (int i = 0; i < 4; i++)
#pragma unroll
            for (int j = 0; j < 2; j++)
                acc[i][j] = __builtin_amdgcn_mfma_f32_16x16x32_bf16(af[i], bfr[j], acc[i][j], 0, 0, 0);
        __builtin_amdgcn_s_setprio(0);
#pragma unroll
        for (int j = 0; j < 2; j++)
            bfr[j] = *(const bf16x8*)&lB[(wn + (2 + j) * 16 + mf) * 64 + sl];
        __builtin_amdgcn_s_setprio(1);
#pragma unroll
        for (int i = 0; i < 4; i++)
#pragma unroll
            for (int j = 0; j < 2; j++)
                acc[i][2 + j] = __builtin_amdgcn_mfma_f32_16x16x32_bf16(af[i], bfr[j], acc[i][2 + j], 0, 0, 0);
        __builtin_amdgcn_s_setprio(0);
    }

    u16* P = (split == 0 ? QT : KT) + (size_t)b * 2097152;
    __syncthreads();
#pragma unroll
    for (int i = 0; i < 4; i++)
#pragma unroll
        for (int r = 0; r < 4; r++) {
            int row = wm + i * 16 + quad * 4 + r;       // 0..127
            int key = row & 7;
#pragma unroll
            for (int j = 0; j < 4; j++) {
                int col = wn + j * 16 + mf;             // 0..255
                lds[row * 256 + (((col >> 3) ^ key) << 3) + (col & 7)] =
                    f2bf(acc[i][j][r]);
            }
        }
    __syncthreads();
    for (int p = 0; p < 8; p++) {
        int idx = p * 512 + t;
        int row = idx >> 5, chunk = idx & 31;
        uint4 v = *(const uint4*)&lds[row * 256 + ((chunk ^ (row & 7)) << 3)];
        *(uint4*)&P[(size_t)(m0 + row) * 512 + n0 + chunk * 8] = v;
    }
}

// ---------------------------------------------------------------------------
// Reduce partials + softmax normalization: OT_b = (P0 + P1) / rowsum.
// Part has 16 panels per row. grid (1024, nb).
// ---------------------------------------------------------------------------
__global__ __launch_bounds__(256) void k_pv_reduce(const u16* __restrict__ QT,
                                                   const u16* __restrict__ KT,
                                                   const float* __restrict__ Part,
                                                   u16* __restrict__ OT,
                                                   int b0) {
    const int b = b0 + blockIdx.y;
    const int t = threadIdx.x;
    __shared__ float sInv[4];
    if (t < 64) {
        int r = t >> 4, which = t & 15;
        int p = blockIdx.x * 4 + r;
        float v = Part[((size_t)b * 16 + which) * 4096 + p];
        for (int off = 8; off > 0; off >>= 1) v += __shfl_xor(v, off);
        if (which == 0) sInv[r] = 1.f / v;
    }
    __syncthreads();
    const float inv = sInv[t >> 6];
    size_t base = (size_t)b * 2097152;
    size_t i0 = base + ((size_t)blockIdx.x * 256 + t) * 8;
    uint4 a = *(const uint4*)(QT + i0);
    uint4 c = *(const uint4*)(KT + i0);
    uint32_t wa[4] = {a.x, a.y, a.z, a.w};
    uint32_t wc[4] = {c.x, c.y, c.z, c.w};
    uint32_t o[4];
    for (int j = 0; j < 4; j++) {
        float lo = (__uint_as_float(wa[j] << 16) + __uint_as_float(wc[j] << 16)) * inv;
        float hi = (__uint_as_float(wa[j] & 0xFFFF0000u) + __uint_as_float(wc[j] & 0xFFFF0000u)) * inv;
        o[j] = (uint32_t)f2bf(lo) | ((uint32_t)f2bf(hi) << 16);
    }
    *(uint4*)(OT + i0) = make_uint4(o[0], o[1], o[2], o[3]);
}

// ---------------------------------------------------------------------------
// Proj + residual (R2-verified form): y = Wp @ OT^T + bp + x. grid (32,4,8).
// 128^2 core at 5 blocks/CU: the 176 MB epilogue stream overlaps across
// resident blocks (256^2 template serialized it -> +59us, R12).
// ---------------------------------------------------------------------------
__global__ __launch_bounds__(256) void k_proj(const u16* __restrict__ Wc,
                                              const u16* __restrict__ OT,
                                              const u16* __restrict__ Bc,
                                              const void* __restrict__ x_raw,
                                              const int* __restrict__ flag,
                                              void* __restrict__ y_raw) {
    __shared__ __align__(16) u16 smu[16384];
    float* smf = (float*)smu;
    int nI, mI, b;
    swz(nI, mI, b);
    const int n0 = nI * 128;
    const int m0 = mI * 128;
    f32x4 acc[4][4];
    gemm_core(Wc + (size_t)3 * 262144, OT + (size_t)b * 2097152, 512, 512, 512,
              m0, n0, smu, smu + 8192, acc);

    const int mode = *flag;
    const u16* bp = Bc + 5 * 512;
    const int t = threadIdx.x;
    const int wave = t >> 6, lane = t & 63;
    const int wn = (wave & 1) * 64;
    const int mf = lane & 15, quad = lane >> 4;
    const int whalf = wave >> 1;
    size_t bb = (size_t)b * 2097152;
    for (int h = 0; h < 2; h++) {
        __syncthreads();
        if (whalf == h) {
            for (int i = 0; i < 4; i++)
                for (int r = 0; r < 4; r++) {
                    int rowl = i * 16 + quad * 4 + r;
                    int kf = ((rowl >> 2) & 1) << 4;
                    for (int j = 0; j < 4; j++) {
                        int col = wn + j * 16 + mf;
                        smf[rowl * 128 + (col ^ kf)] = acc[i][j][r];
                    }
                }
        }
        __syncthreads();
        const int rowbase = m0 + h * 64;
        if (mode) {
            for (int p = 0; p < 8; p++) {
                int idx = p * 256 + t;
                int rowl = idx >> 5, c4 = (idx & 31) * 4;
                int kf = ((rowl >> 2) & 1) << 4;
                f32x4 v = *(const f32x4*)&smf[rowl * 128 + (c4 ^ kf)];
                int rowg = rowbase + rowl;
                float bias = bf2f(bp[rowg]);
                size_t o = bb + (size_t)rowg * 4096 + n0 + c4;
                float4 xv = *(const float4*)((const float*)x_raw + o);
                float4 out = make_float4(v[0] + bias + xv.x, v[1] + bias + xv.y,
                                         v[2] + bias + xv.z, v[3] + bias + xv.w);
                *(float4*)((float*)y_raw + o) = out;
            }
        } else {
            for (int p = 0; p < 4; p++) {
                int idx = p * 256 + t;
                int rowl = idx >> 4, c8 = (idx & 15) * 8;
                int kf = ((rowl >> 2) & 1) << 4;
                const float* sp = &smf[rowl * 128 + (c8 ^ kf)];
                f32x4 v0 = *(const f32x4*)sp;
                f32x4 v1 = *(const f32x4*)(sp + 4);
                int rowg = rowbase + rowl;
                float bias = bf2f(bp[rowg]);
                size_t o = bb + (size_t)rowg * 4096 + n0 + c8;
                uint4 xv = *(const uint4*)((const u16*)x_raw + o);
                uint32_t xw[4] = {xv.x, xv.y, xv.z, xv.w};
                float vals[8] = {v0[0], v0[1], v0[2], v0[3],
                                 v1[0], v1[1], v1[2], v1[3]};
                uint32_t ow[4];
                for (int q2 = 0; q2 < 4; q2++) {
                    float lo = __uint_as_float(xw[q2] << 16) + vals[2 * q2] + bias;
                    float hi = __uint_as_float(xw[q2] & 0xFFFF0000u) + vals[2 * q2 + 1] + bias;
                    ow[q2] = (uint32_t)f2bf(lo) | ((uint32_t)f2bf(hi) << 16);
                }
                *(uint4*)((u16*)y_raw + o) = make_uint4(ow[0], ow[1], ow[2], ow[3]);
            }
        }
    }
}

// ---------------------------------------------------------------------------
extern "C" void kernel_launch(void* const* d_in, const int* in_sizes, int n_in,
                              void* d_out, int out_size, void* d_ws, size_t ws_size,
                              hipStream_t stream) {
    (void)in_sizes; (void)n_in; (void)out_size;
    const void* x  = d_in[0];
    const void* gw = d_in[1];
    const void* gb = d_in[2];
    const void* wq = d_in[3];
    const void* bq = d_in[4];
    const void* wk = d_in[5];
    const void* bk = d_in[6];
    const void* wv = d_in[7];
    const void* bv = d_in[8];
    const void* wp = d_in[9];
    const void* bp = d_in[10];

    u16* ws16 = (u16*)d_ws;
    int* flag = (int*)d_ws;                 // u16 elems 0..15
    float* Sc = (float*)(ws16 + 16);        // 4096 f32
    float* Sh = Sc + 4096;                  // 4096 f32
    u16* Wc = ws16 + 16 + 16384;            // 1048576
    u16* Bc = Wc + 1048576;                 // 4096
    u16* HT = Bc + 4096;                    // 16777216 (S slot 0 after qkv)
    u16* QT = HT + 16777216;
    u16* KT = QT + 16777216;
    u16* V  = KT + 16777216;
    u16* OT = V  + 16777216;
    float* Part = (float*)(OT + 16777216);  // reserved 4 MB (uses 2 MB)
    u16* Tail = (u16*)(Part + 1048576);     // S slots 1..nb-1
    const size_t base_elems = (size_t)(Tail - ws16);

    int nb = 1;
    for (int cand = 8; cand >= 2; cand >>= 1) {
        size_t need = 2ull * (base_elems + (size_t)(cand - 1) * 16777216ull);
        if (ws_size >= need) { nb = cand; break; }
    }

    k_detect<<<1, 256, 0, stream>>>((const u16*)x, flag);
    k_cvt_wb<<<4108, 256, 0, stream>>>(wq, wk, wv, wp, gw, gb, bq, bk, bv, bp,
                                       flag, Wc, Bc);
    k_gn_stats<<<256, 256, 0, stream>>>(x, Bc, flag, Sc, Sh);
    k_gn_apply<<<dim3(64, 8), 256, 0, stream>>>(x, flag, Sc, Sh, HT);
    k_qkv<<<dim3(32, 24), 512, 0, stream>>>(HT, Wc, Bc, QT, KT, V);
    for (int b0 = 0; b0 < 8; b0 += nb) {
        k_scores<<<dim3(16, 16, nb), 512, 0, stream>>>(QT, KT, HT, Tail, Part, b0);
        k_pv_split<<<dim3(2, 32, 2 * nb), 512, 0, stream>>>(HT, Tail, V, QT, KT, b0);
        k_pv_reduce<<<dim3(1024, nb), 256, 0, stream>>>(QT, KT, Part, OT, b0);
    }
    k_proj<<<dim3(32, 4, 8), 256, 0, stream>>>(Wc, OT, Bc, x, flag, d_out);
}